// Round 5
// baseline (6374.517 us; speedup 1.0000x reference)
//
#include <hip/hip_runtime.h>

#define SEQ_LEN 256
#define SPIKE_STEPS 7
#define BATCH 128
#define IN_DIM 96
#define HIDDEN 512
#define OUT_DIM 2

// d_ws layout (f32 weights):
//   W0T [96*512] | W1T [512*512] | W2T [512*512] | ctr | zbuf[B][256][56]u64
#define W0T_OFF 0
#define W1T_OFF (IN_DIM * HIDDEN)
#define W2T_OFF (W1T_OFF + HIDDEN * HIDDEN)
#define CTR_BYTE_OFF ((size_t)(W2T_OFF + HIDDEN * HIDDEN) * sizeof(float))
#define ZBUF_BYTE_OFF (CTR_BYTE_OFF + 1024)

typedef float f32x4 __attribute__((ext_vector_type(4)));
typedef float f32x2 __attribute__((ext_vector_type(2)));

__global__ void transpose_kernel(const float* __restrict__ in, float* __restrict__ out,
                                 int rows, int cols) {
    int idx = blockIdx.x * blockDim.x + threadIdx.x;
    if (idx < rows * cols) {
        int r = idx / cols, c = idx - r * cols;
        out[c * rows + r] = in[idx];
    }
}

// Packed f32 fma: acc.{lo,hi} += w * m.{lo,hi}. __builtin_elementwise_fma on
// <2 x float> lowers to v_pk_fma_f32 (VOP3P) on gfx950; the compiler encodes
// the w-splat via op_sel, no explicit mov. Each half is an independent IEEE
// RN fma => bit-identical to two scalar __fmaf_rn.
__device__ __forceinline__ void pkfma(f32x2& acc, float w, f32x2 m) {
    const f32x2 wv = {w, w};
    acc = __builtin_elementwise_fma(wv, m, acc);
}

// Dense masked 7-step row sum over ALL 512 rows. Bit-identical to the
// union-list version: rows inactive in step s contribute fma(0.0, w, acc)
// == acc exactly (acc is never -0: starts +0, and +0 + +/-0 = +0 in RN;
// a partial sum hitting exact 0 is +0 in RN). Step-pair packing keeps each
// step's sum in strictly ascending row order => same rounding as R3-passing
// kernel. Sequential streaming addresses => no act list, no address chains.
// 16-row software pipeline (next group's global loads in flight during
// current group's fmas).
__device__ __forceinline__ void dense_sum7(const float* __restrict__ W,
                                           const float (* __restrict__ fm)[8],
                                           int tid,
                                           f32x2& a0, f32x2& a1, f32x2& a2, f32x2& a3) {
    const float* Wt = W + tid;
    float buf[16];
    #pragma unroll
    for (int k = 0; k < 16; ++k) buf[k] = Wt[k * HIDDEN];
    #pragma unroll 1
    for (int n = 16; n < HIDDEN; n += 16) {
        float nxt[16];
        #pragma unroll
        for (int k = 0; k < 16; ++k) nxt[k] = Wt[(n + k) * HIDDEN];
        #pragma unroll
        for (int k = 0; k < 16; ++k) {
            const int r = n - 16 + k;
            f32x4 fa = *reinterpret_cast<const f32x4*>(&fm[r][0]);
            f32x4 fb = *reinterpret_cast<const f32x4*>(&fm[r][4]);
            pkfma(a0, buf[k], __builtin_shufflevector(fa, fa, 0, 1));
            pkfma(a1, buf[k], __builtin_shufflevector(fa, fa, 2, 3));
            pkfma(a2, buf[k], __builtin_shufflevector(fb, fb, 0, 1));
            pkfma(a3, buf[k], __builtin_shufflevector(fb, fb, 2, 3));
        }
        #pragma unroll
        for (int k = 0; k < 16; ++k) buf[k] = nxt[k];
    }
    #pragma unroll
    for (int k = 0; k < 16; ++k) {
        const int r = HIDDEN - 16 + k;
        f32x4 fa = *reinterpret_cast<const f32x4*>(&fm[r][0]);
        f32x4 fb = *reinterpret_cast<const f32x4*>(&fm[r][4]);
        pkfma(a0, buf[k], __builtin_shufflevector(fa, fa, 0, 1));
        pkfma(a1, buf[k], __builtin_shufflevector(fa, fa, 2, 3));
        pkfma(a2, buf[k], __builtin_shufflevector(fb, fb, 0, 1));
        pkfma(a3, buf[k], __builtin_shufflevector(fb, fb, 2, 3));
    }
}

// Two-stage pipeline: even blocks = producer (layer0+layer1), odd = consumer
// (layer2+output). Handoff granularity = one seq step (7 masks at once).
__launch_bounds__(512, 1)
__global__ void snn_pipe_kernel(const float* __restrict__ x,     // [256,128,96]
                                const float* __restrict__ Wout,  // [2,512]
                                const float* __restrict__ betas, // [3]
                                const float* __restrict__ thrs,  // [3]
                                const float* __restrict__ W0T,   // [96,512]
                                const float* __restrict__ W1T,   // [512,512]
                                const float* __restrict__ W2T,   // [512,512]
                                unsigned long long* __restrict__ zbuf,
                                int* __restrict__ ctr,
                                float* __restrict__ out)         // [256,128,2]
{
    const int b    = blockIdx.x >> 1;
    const int role = blockIdx.x & 1;
    const int tid  = threadIdx.x;
    const int lane = tid & 63;
    const int wid  = tid >> 6;

    __shared__ float xs[IN_DIM];
    __shared__ unsigned long long zm7[SPIKE_STEPS][8];
    __shared__ __align__(16) float fm[HIDDEN][8];   // 16 KB per-row step masks
    __shared__ float red[16];

    if (role == 0) {
        // ---------------- producer: layer0 + layer1 ----------------
        const float beta0 = betas[0], beta1 = betas[1];
        const float thr0  = thrs[0],  thr1  = thrs[1];
        float mem0 = 0.f, mem1 = 0.f;
        unsigned long long* zb = zbuf + (size_t)b * SEQ_LEN * 56;

        for (int i = 0; i < SEQ_LEN; ++i) {
            if (tid < IN_DIM) xs[tid] = x[(i * BATCH + b) * IN_DIM + tid];
            __syncthreads();                                        // B1

            float cur0 = 0.f;
            #pragma unroll 8
            for (int k = 0; k < IN_DIM; ++k)
                cur0 = __fmaf_rn(xs[k], W0T[k * HIDDEN + tid], cur0);

            // layer-0 recurrence is autonomous within the seq step:
            // compute all 7 z0 mask floats for this thread's row.
            f32x4 v0 = {0.f, 0.f, 0.f, 0.f};
            f32x4 v4 = {0.f, 0.f, 0.f, 0.f};
            #pragma unroll
            for (int s = 0; s < SPIKE_STEPS; ++s) {
                bool reset0 = (mem0 - thr0) > 0.f;
                mem0 = reset0 ? 0.f : __fadd_rn(__fmul_rn(beta0, mem0), cur0);
                bool z0 = (mem0 - thr0) > 0.f;
                float zf = z0 ? 1.0f : 0.0f;
                if (s < 4) v0[s] = zf; else v4[s - 4] = zf;
            }
            *reinterpret_cast<f32x4*>(&fm[tid][0]) = v0;
            *reinterpret_cast<f32x4*>(&fm[tid][4]) = v4;
            __syncthreads();                                        // B2

            f32x2 a0 = {0.f, 0.f}, a1 = {0.f, 0.f}, a2 = {0.f, 0.f}, a3 = {0.f, 0.f};
            dense_sum7(W1T, fm, tid, a0, a1, a2, a3);
            const float accs[SPIKE_STEPS] = {a0.x, a0.y, a1.x, a1.y, a2.x, a2.y, a3.x};

            // layer-1 recurrence over the 7 steps, emit z1 masks
            #pragma unroll
            for (int s = 0; s < SPIKE_STEPS; ++s) {
                bool reset1 = (mem1 - thr1) > 0.f;
                mem1 = reset1 ? 0.f : __fadd_rn(__fmul_rn(beta1, mem1), accs[s]);
                bool z1 = (mem1 - thr1) > 0.f;
                unsigned long long bal1 = __ballot(z1);
                if (lane == 0)
                    __hip_atomic_store(&zb[(size_t)i * 56 + s * 8 + wid], bal1,
                                       __ATOMIC_RELAXED, __HIP_MEMORY_SCOPE_AGENT);
            }
            __syncthreads();   // B3: all waves' mask stores drained (vmcnt 0)
            if (tid == 0)
                __hip_atomic_store(&ctr[b], i + 1,
                                   __ATOMIC_RELAXED, __HIP_MEMORY_SCOPE_AGENT);
        }
    } else {
        // ---------------- consumer: layer2 + output ----------------
        const float beta2 = betas[2];
        const float thr2  = thrs[2];
        const float wo0 = Wout[tid];
        const float wo1 = Wout[HIDDEN + tid];
        float mem2 = 0.f;
        // Deferred output reduction: per-thread integrator a, prefix
        // accumulator w; one cross-thread reduction per seq step.
        float a0s = 0.f, a1s = 0.f;
        const unsigned long long* zb = zbuf + (size_t)b * SEQ_LEN * 56;

        for (int i = 0; i < SEQ_LEN; ++i) {
            if (tid == 0) {
                while (__hip_atomic_load(&ctr[b], __ATOMIC_RELAXED,
                                         __HIP_MEMORY_SCOPE_AGENT) < i + 1)
                    __builtin_amdgcn_s_sleep(1);
            }
            __syncthreads();                                        // B1

            if (tid < 56)
                ((unsigned long long*)zm7)[tid] =
                    __hip_atomic_load(&zb[(size_t)i * 56 + tid],
                                      __ATOMIC_RELAXED, __HIP_MEMORY_SCOPE_AGENT);
            __syncthreads();                                        // B2

            f32x4 v0 = {0.f, 0.f, 0.f, 0.f};
            f32x4 v4 = {0.f, 0.f, 0.f, 0.f};
            #pragma unroll
            for (int s = 0; s < SPIKE_STEPS; ++s) {
                float zf = ((zm7[s][wid] >> lane) & 1ull) ? 1.0f : 0.0f;
                if (s < 4) v0[s] = zf; else v4[s - 4] = zf;
            }
            *reinterpret_cast<f32x4*>(&fm[tid][0]) = v0;
            *reinterpret_cast<f32x4*>(&fm[tid][4]) = v4;
            __syncthreads();                                        // B3

            f32x2 c0 = {0.f, 0.f}, c1 = {0.f, 0.f}, c2 = {0.f, 0.f}, c3 = {0.f, 0.f};
            dense_sum7(W2T, fm, tid, c0, c1, c2, c3);
            const float accs[SPIKE_STEPS] = {c0.x, c0.y, c1.x, c1.y, c2.x, c2.y, c3.x};

            float w0 = 0.f, w1 = 0.f;
            #pragma unroll
            for (int s = 0; s < SPIKE_STEPS; ++s) {
                bool reset2 = (mem2 - thr2) > 0.f;
                mem2 = reset2 ? 0.f : __fadd_rn(__fmul_rn(beta2, mem2), accs[s]);
                bool z2 = (mem2 - thr2) > 0.f;
                a0s += z2 ? wo0 : 0.f;
                a1s += z2 ? wo1 : 0.f;
                w0 += a0s;
                w1 += a1s;
            }

            // one cross-thread reduction per seq step
            float r0 = w0, r1 = w1;
            #pragma unroll
            for (int off = 32; off > 0; off >>= 1) {
                r0 += __shfl_down(r0, off);
                r1 += __shfl_down(r1, off);
            }
            if (lane == 0) { red[wid * 2] = r0; red[wid * 2 + 1] = r1; }
            __syncthreads();                                        // B4
            if (tid == 0) {
                float s0 = 0.f, s1 = 0.f;
                #pragma unroll
                for (int q = 0; q < 8; ++q) { s0 += red[q * 2]; s1 += red[q * 2 + 1]; }
                out[(i * BATCH + b) * OUT_DIM + 0] = s0 / 7.0f;
                out[(i * BATCH + b) * OUT_DIM + 1] = s1 / 7.0f;
            }
            // next write to red is a full seq step away (>=3 barriers) and
            // tid0's read precedes its next barrier => no extra barrier.
        }
    }
}

extern "C" void kernel_launch(void* const* d_in, const int* in_sizes, int n_in,
                              void* d_out, int out_size, void* d_ws, size_t ws_size,
                              hipStream_t stream) {
    const float* x     = (const float*)d_in[0];
    const float* W0    = (const float*)d_in[1];
    const float* W1    = (const float*)d_in[2];
    const float* W2    = (const float*)d_in[3];
    const float* Wout  = (const float*)d_in[4];
    const float* betas = (const float*)d_in[5];
    const float* thrs  = (const float*)d_in[6];
    float* out = (float*)d_out;

    float* ws  = (float*)d_ws;
    float* W0T = ws + W0T_OFF;
    float* W1T = ws + W1T_OFF;
    float* W2T = ws + W2T_OFF;
    int* ctr = (int*)((char*)d_ws + CTR_BYTE_OFF);
    unsigned long long* zbuf = (unsigned long long*)((char*)d_ws + ZBUF_BYTE_OFF);

    {
        int n = HIDDEN * IN_DIM;
        transpose_kernel<<<(n + 255) / 256, 256, 0, stream>>>(W0, W0T, HIDDEN, IN_DIM);
    }
    {
        int n = HIDDEN * HIDDEN;
        transpose_kernel<<<(n + 255) / 256, 256, 0, stream>>>(W1, W1T, HIDDEN, HIDDEN);
        transpose_kernel<<<(n + 255) / 256, 256, 0, stream>>>(W2, W2T, HIDDEN, HIDDEN);
    }

    hipMemsetAsync((char*)d_ws + CTR_BYTE_OFF, 0, 1024, stream);

    snn_pipe_kernel<<<2 * BATCH, HIDDEN, 0, stream>>>(
        x, Wout, betas, thrs, W0T, W1T, W2T, zbuf, ctr, out);
}

// Round 6
// 4897.788 us; speedup vs baseline: 1.3015x; 1.3015x over previous
//
#include <hip/hip_runtime.h>

#define SEQ_LEN 256
#define SPIKE_STEPS 7
#define BATCH 128
#define IN_DIM 96
#define HIDDEN 512
#define OUT_DIM 2

// d_ws layout (f32 weights, no pad rows):
//   W0T [96*512] | W1T [512*512] | W2T [512*512] | ctr | zbuf[B][256][56]u64
#define W0T_OFF 0
#define W1T_OFF (IN_DIM * HIDDEN)
#define W2T_OFF (W1T_OFF + HIDDEN * HIDDEN)
#define CTR_BYTE_OFF ((size_t)(W2T_OFF + HIDDEN * HIDDEN) * sizeof(float))
#define ZBUF_BYTE_OFF (CTR_BYTE_OFF + 1024)

__global__ void transpose_kernel(const float* __restrict__ in, float* __restrict__ out,
                                 int rows, int cols) {
    int idx = blockIdx.x * blockDim.x + threadIdx.x;
    if (idx < rows * cols) {
        int r = idx / cols, c = idx - r * cols;
        out[c * rows + r] = in[idx];
    }
}

// Union-batched 7-step row sum, SGPR-mask edition.
// Per union row the ONLY LDS traffic is one broadcast ds_read_b32 of a packed
// entry  e = row | (m7<<16).  readfirstlane moves e to an SGPR, so the mask
// bit tests + float selects compile to SALU (s_bfe/s_cselect) that co-issues
// with other waves' VALU; the per-(row,step) VALU cost is a single
// v_fma_f32 acc, s_mask, w, acc.
// Numerics: per step s the sum visits union rows in ascending order; active
// rows add fma(1.0,w,acc)=RN(acc+w); inactive/pad rows add fma(0.0,w,acc)
// = acc exactly (acc is never -0: starts +0, +0 + +/-0 = +0 in RN). Pad
// entries are 0 = (row 0, mask 0): they load a VALID weight (no NaN*0
// hazard) and contribute nothing. => bit-identical to the R3-passing kernel.
// 16-entry software pipeline: next group's entry reads + weight loads are
// issued before the current group's fmas.
__device__ __forceinline__ void union_sum7(const float* __restrict__ W,
                                           const int* __restrict__ act,
                                           int npad, int tid,
                                           float* __restrict__ acc) {
    if (npad <= 0) return;
    unsigned uc[16]; float wc[16];
    #pragma unroll
    for (int k = 0; k < 16; ++k) {
        unsigned u = (unsigned)__builtin_amdgcn_readfirstlane(act[k]);
        uc[k] = u;
        wc[k] = W[(u & 0xFFFFu) * HIDDEN + tid];
    }
    for (int n = 16; n < npad; n += 16) {
        unsigned un[16]; float wn[16];
        #pragma unroll
        for (int k = 0; k < 16; ++k) {
            unsigned u = (unsigned)__builtin_amdgcn_readfirstlane(act[n + k]);
            un[k] = u;
            wn[k] = W[(u & 0xFFFFu) * HIDDEN + tid];
        }
        #pragma unroll
        for (int k = 0; k < 16; ++k) {
            #pragma unroll
            for (int s = 0; s < SPIKE_STEPS; ++s) {
                float mf = ((uc[k] >> (16 + s)) & 1u) ? 1.0f : 0.0f;  // SALU
                acc[s] = __fmaf_rn(mf, wc[k], acc[s]);                 // 1 VALU
            }
        }
        #pragma unroll
        for (int k = 0; k < 16; ++k) { uc[k] = un[k]; wc[k] = wn[k]; }
    }
    #pragma unroll
    for (int k = 0; k < 16; ++k) {
        #pragma unroll
        for (int s = 0; s < SPIKE_STEPS; ++s) {
            float mf = ((uc[k] >> (16 + s)) & 1u) ? 1.0f : 0.0f;
            acc[s] = __fmaf_rn(mf, wc[k], acc[s]);
        }
    }
}

// Build the union active list with packed per-row step masks.
// m7 = this thread's 7 firing bits. Rank = compact ascending index over the
// union mask => same ascending add order as R3.
__device__ __forceinline__ int build_union(const unsigned long long (*zm7)[8],
                                           int* act,
                                           int wid, int lane, int tid, int m7) {
    unsigned long long um[8];
    #pragma unroll
    for (int q = 0; q < 8; ++q) {
        unsigned long long u = zm7[0][q];
        #pragma unroll
        for (int s = 1; s < SPIKE_STEPS; ++s) u |= zm7[s][q];
        um[q] = u;
    }
    int pre = 0, total = 0;
    #pragma unroll
    for (int q = 0; q < 8; ++q) {
        int p = __popcll(um[q]);
        total += p;
        if (q < wid) pre += p;
    }
    if (m7 != 0) {
        int rank = pre + __popcll(um[wid] & ((1ull << lane) - 1ull));
        act[rank] = tid | (m7 << 16);
    }
    int npad = (total + 15) & ~15;
    if (tid < npad - total) act[total + tid] = 0;   // row 0, mask 0 pad
    return npad;
}

// Two-stage pipeline: even blocks = producer (layer0+layer1), odd = consumer
// (layer2+output). Handoff granularity = one seq step (7 masks at once).
__launch_bounds__(512, 1)
__global__ void snn_pipe_kernel(const float* __restrict__ x,     // [256,128,96]
                                const float* __restrict__ Wout,  // [2,512]
                                const float* __restrict__ betas, // [3]
                                const float* __restrict__ thrs,  // [3]
                                const float* __restrict__ W0T,   // [96,512]
                                const float* __restrict__ W1T,   // [512,512]
                                const float* __restrict__ W2T,   // [512,512]
                                unsigned long long* __restrict__ zbuf,
                                int* __restrict__ ctr,
                                float* __restrict__ out)         // [256,128,2]
{
    const int b    = blockIdx.x >> 1;
    const int role = blockIdx.x & 1;
    const int tid  = threadIdx.x;
    const int lane = tid & 63;
    const int wid  = tid >> 6;

    __shared__ float xs[IN_DIM];
    __shared__ unsigned long long zm7[SPIKE_STEPS][8];
    __shared__ int act[HIDDEN];
    __shared__ float red[16];

    if (role == 0) {
        // ---------------- producer: layer0 + layer1 ----------------
        const float beta0 = betas[0], beta1 = betas[1];
        const float thr0  = thrs[0],  thr1  = thrs[1];
        float mem0 = 0.f, mem1 = 0.f;
        unsigned long long* zb = zbuf + (size_t)b * SEQ_LEN * 56;

        for (int i = 0; i < SEQ_LEN; ++i) {
            if (tid < IN_DIM) xs[tid] = x[(i * BATCH + b) * IN_DIM + tid];
            __syncthreads();                                        // B1

            float cur0 = 0.f;
            #pragma unroll 8
            for (int k = 0; k < IN_DIM; ++k)
                cur0 = __fmaf_rn(xs[k], W0T[k * HIDDEN + tid], cur0);

            // layer-0 recurrence is autonomous within the seq step:
            // compute all 7 z0 masks upfront.
            int m7 = 0;
            #pragma unroll
            for (int s = 0; s < SPIKE_STEPS; ++s) {
                bool reset0 = (mem0 - thr0) > 0.f;
                mem0 = reset0 ? 0.f : __fadd_rn(__fmul_rn(beta0, mem0), cur0);
                bool z0 = (mem0 - thr0) > 0.f;
                m7 |= (int)z0 << s;
                unsigned long long bal = __ballot(z0);
                if (lane == 0) zm7[s][wid] = bal;
            }
            __syncthreads();                                        // B2

            int npad = build_union(zm7, act, wid, lane, tid, m7);
            __syncthreads();                                        // B3

            float accs[SPIKE_STEPS] = {0.f, 0.f, 0.f, 0.f, 0.f, 0.f, 0.f};
            union_sum7(W1T, act, npad, tid, accs);

            // layer-1 recurrence over the 7 steps, emit z1 masks
            #pragma unroll
            for (int s = 0; s < SPIKE_STEPS; ++s) {
                bool reset1 = (mem1 - thr1) > 0.f;
                mem1 = reset1 ? 0.f : __fadd_rn(__fmul_rn(beta1, mem1), accs[s]);
                bool z1 = (mem1 - thr1) > 0.f;
                unsigned long long bal1 = __ballot(z1);
                if (lane == 0)
                    __hip_atomic_store(&zb[(size_t)i * 56 + s * 8 + wid], bal1,
                                       __ATOMIC_RELAXED, __HIP_MEMORY_SCOPE_AGENT);
            }
            __syncthreads();   // B4: all waves' mask stores drained (vmcnt 0)
            if (tid == 0)
                __hip_atomic_store(&ctr[b], i + 1,
                                   __ATOMIC_RELAXED, __HIP_MEMORY_SCOPE_AGENT);
        }
    } else {
        // ---------------- consumer: layer2 + output ----------------
        const float beta2 = betas[2];
        const float thr2  = thrs[2];
        const float wo0 = Wout[tid];
        const float wo1 = Wout[HIDDEN + tid];
        float mem2 = 0.f;
        // Deferred output reduction: per-thread integrator a, prefix
        // accumulator w; one cross-thread reduction per seq step.
        float a0s = 0.f, a1s = 0.f;
        const unsigned long long* zb = zbuf + (size_t)b * SEQ_LEN * 56;

        for (int i = 0; i < SEQ_LEN; ++i) {
            if (tid == 0) {
                while (__hip_atomic_load(&ctr[b], __ATOMIC_RELAXED,
                                         __HIP_MEMORY_SCOPE_AGENT) < i + 1)
                    __builtin_amdgcn_s_sleep(1);
            }
            __syncthreads();                                        // B1

            if (tid < 56)
                ((unsigned long long*)zm7)[tid] =
                    __hip_atomic_load(&zb[(size_t)i * 56 + tid],
                                      __ATOMIC_RELAXED, __HIP_MEMORY_SCOPE_AGENT);
            __syncthreads();                                        // B2

            int m7 = 0;
            #pragma unroll
            for (int s = 0; s < SPIKE_STEPS; ++s)
                m7 |= (int)((zm7[s][wid] >> lane) & 1ull) << s;

            int npad = build_union(zm7, act, wid, lane, tid, m7);
            __syncthreads();                                        // B3

            float accs[SPIKE_STEPS] = {0.f, 0.f, 0.f, 0.f, 0.f, 0.f, 0.f};
            union_sum7(W2T, act, npad, tid, accs);

            float w0 = 0.f, w1 = 0.f;
            #pragma unroll
            for (int s = 0; s < SPIKE_STEPS; ++s) {
                bool reset2 = (mem2 - thr2) > 0.f;
                mem2 = reset2 ? 0.f : __fadd_rn(__fmul_rn(beta2, mem2), accs[s]);
                bool z2 = (mem2 - thr2) > 0.f;
                a0s += z2 ? wo0 : 0.f;
                a1s += z2 ? wo1 : 0.f;
                w0 += a0s;
                w1 += a1s;
            }

            // one cross-thread reduction per seq step
            float r0 = w0, r1 = w1;
            #pragma unroll
            for (int off = 32; off > 0; off >>= 1) {
                r0 += __shfl_down(r0, off);
                r1 += __shfl_down(r1, off);
            }
            if (lane == 0) { red[wid * 2] = r0; red[wid * 2 + 1] = r1; }
            __syncthreads();                                        // B4
            if (tid == 0) {
                float s0 = 0.f, s1 = 0.f;
                #pragma unroll
                for (int q = 0; q < 8; ++q) { s0 += red[q * 2]; s1 += red[q * 2 + 1]; }
                out[(i * BATCH + b) * OUT_DIM + 0] = s0 / 7.0f;
                out[(i * BATCH + b) * OUT_DIM + 1] = s1 / 7.0f;
            }
            // next write to red is a full seq step away (>=3 barriers) and
            // tid0's read precedes its next barrier => no extra barrier.
        }
    }
}

extern "C" void kernel_launch(void* const* d_in, const int* in_sizes, int n_in,
                              void* d_out, int out_size, void* d_ws, size_t ws_size,
                              hipStream_t stream) {
    const float* x     = (const float*)d_in[0];
    const float* W0    = (const float*)d_in[1];
    const float* W1    = (const float*)d_in[2];
    const float* W2    = (const float*)d_in[3];
    const float* Wout  = (const float*)d_in[4];
    const float* betas = (const float*)d_in[5];
    const float* thrs  = (const float*)d_in[6];
    float* out = (float*)d_out;

    float* ws  = (float*)d_ws;
    float* W0T = ws + W0T_OFF;
    float* W1T = ws + W1T_OFF;
    float* W2T = ws + W2T_OFF;
    int* ctr = (int*)((char*)d_ws + CTR_BYTE_OFF);
    unsigned long long* zbuf = (unsigned long long*)((char*)d_ws + ZBUF_BYTE_OFF);

    {
        int n = HIDDEN * IN_DIM;
        transpose_kernel<<<(n + 255) / 256, 256, 0, stream>>>(W0, W0T, HIDDEN, IN_DIM);
    }
    {
        int n = HIDDEN * HIDDEN;
        transpose_kernel<<<(n + 255) / 256, 256, 0, stream>>>(W1, W1T, HIDDEN, HIDDEN);
        transpose_kernel<<<(n + 255) / 256, 256, 0, stream>>>(W2, W2T, HIDDEN, HIDDEN);
    }

    hipMemsetAsync((char*)d_ws + CTR_BYTE_OFF, 0, 1024, stream);

    snn_pipe_kernel<<<2 * BATCH, HIDDEN, 0, stream>>>(
        x, Wout, betas, thrs, W0T, W1T, W2T, zbuf, ctr, out);
}

// Round 7
// 2945.943 us; speedup vs baseline: 2.1638x; 1.6626x over previous
//
#include <hip/hip_runtime.h>

#define SEQ_LEN 256
#define SPIKE_STEPS 7
#define BATCH 128
#define IN_DIM 96
#define HIDDEN 512
#define OUT_DIM 2

// d_ws layout (f32 weights):
//   W0T [96*512] | W1T [512*512] | W2T [512*512] | ctr | zbuf[B][256][56]u64
#define W0T_OFF 0
#define W1T_OFF (IN_DIM * HIDDEN)
#define W2T_OFF (W1T_OFF + HIDDEN * HIDDEN)
#define CTR_BYTE_OFF ((size_t)(W2T_OFF + HIDDEN * HIDDEN) * sizeof(float))
#define ZBUF_BYTE_OFF (CTR_BYTE_OFF + 1024)

typedef float f32x4 __attribute__((ext_vector_type(4)));
typedef float f32x2 __attribute__((ext_vector_type(2)));

__global__ void transpose_kernel(const float* __restrict__ in, float* __restrict__ out,
                                 int rows, int cols) {
    int idx = blockIdx.x * blockDim.x + threadIdx.x;
    if (idx < rows * cols) {
        int r = idx / cols, c = idx - r * cols;
        out[c * rows + r] = in[idx];
    }
}

// Packed f32 fma: acc.{lo,hi} += w * m.{lo,hi}. Lowers to v_pk_fma_f32
// (VOP3P) on gfx950 (proven in R5). Each half is an independent IEEE RN fma
// => bit-identical to two scalar __fmaf_rn. Step-pair packing: the two
// halves belong to DIFFERENT steps' accumulator chains, so no reordering
// within any step's sum.
__device__ __forceinline__ void pkfma(f32x2& acc, float w, f32x2 m) {
    const f32x2 wv = {w, w};
    acc = __builtin_elementwise_fma(wv, m, acc);
}

// Union-batched 7-step row sum, rank-indexed masks.
// Key latency fix vs R3/R6: the mask array fmp is indexed by RANK (loop
// index), not by neuron id — so its ds_read_b128 addresses carry no
// dependency on the act-entry loads and the compiler can hoist them deep.
// act entries are read 16-at-a-time as int4 (contiguous broadcast), one
// lgkm batch per group. Weights are software-pipelined one 16-group ahead.
// Numerics: per step s the sum visits union rows in ascending rank order;
// active rows add fma(1,w,acc)=RN(acc+w); inactive rows add fma(0,w,acc)
// = acc exactly (acc never -0: starts +0, +0 + +/-0 = +0 in RN). Pads are
// (row 0, mask 0): load a VALID weight, contribute nothing.
// => bit-identical to the R3-passing kernel (absmax must be exactly 0.25).
__device__ __forceinline__ void union_sum7(const float* __restrict__ W,
                                           const int* __restrict__ act,
                                           const float (* __restrict__ fmp)[8],
                                           int npad, int tid,
                                           f32x2* __restrict__ acc) {
    if (npad <= 0) return;
    const float* Wt = W + tid;
    int rows[16];
    float wc[16];
    {
        const int4* av = reinterpret_cast<const int4*>(act);
        int4 a0 = av[0], a1 = av[1], a2 = av[2], a3 = av[3];
        rows[0]=a0.x; rows[1]=a0.y; rows[2]=a0.z; rows[3]=a0.w;
        rows[4]=a1.x; rows[5]=a1.y; rows[6]=a1.z; rows[7]=a1.w;
        rows[8]=a2.x; rows[9]=a2.y; rows[10]=a2.z; rows[11]=a2.w;
        rows[12]=a3.x; rows[13]=a3.y; rows[14]=a3.z; rows[15]=a3.w;
    }
    #pragma unroll
    for (int k = 0; k < 16; ++k) wc[k] = Wt[rows[k] * HIDDEN];

    for (int n = 16; n < npad; n += 16) {
        int nrows[16];
        float wn[16];
        {
            const int4* av = reinterpret_cast<const int4*>(act + n);
            int4 a0 = av[0], a1 = av[1], a2 = av[2], a3 = av[3];
            nrows[0]=a0.x; nrows[1]=a0.y; nrows[2]=a0.z; nrows[3]=a0.w;
            nrows[4]=a1.x; nrows[5]=a1.y; nrows[6]=a1.z; nrows[7]=a1.w;
            nrows[8]=a2.x; nrows[9]=a2.y; nrows[10]=a2.z; nrows[11]=a2.w;
            nrows[12]=a3.x; nrows[13]=a3.y; nrows[14]=a3.z; nrows[15]=a3.w;
        }
        #pragma unroll
        for (int k = 0; k < 16; ++k) wn[k] = Wt[nrows[k] * HIDDEN];

        const int base = n - 16;
        #pragma unroll
        for (int k = 0; k < 16; ++k) {
            f32x4 fa = *reinterpret_cast<const f32x4*>(&fmp[base + k][0]);
            f32x4 fb = *reinterpret_cast<const f32x4*>(&fmp[base + k][4]);
            pkfma(acc[0], wc[k], __builtin_shufflevector(fa, fa, 0, 1));
            pkfma(acc[1], wc[k], __builtin_shufflevector(fa, fa, 2, 3));
            pkfma(acc[2], wc[k], __builtin_shufflevector(fb, fb, 0, 1));
            pkfma(acc[3], wc[k], __builtin_shufflevector(fb, fb, 2, 3));
        }
        #pragma unroll
        for (int k = 0; k < 16; ++k) wc[k] = wn[k];
    }
    const int base = npad - 16;
    #pragma unroll
    for (int k = 0; k < 16; ++k) {
        f32x4 fa = *reinterpret_cast<const f32x4*>(&fmp[base + k][0]);
        f32x4 fb = *reinterpret_cast<const f32x4*>(&fmp[base + k][4]);
        pkfma(acc[0], wc[k], __builtin_shufflevector(fa, fa, 0, 1));
        pkfma(acc[1], wc[k], __builtin_shufflevector(fa, fa, 2, 3));
        pkfma(acc[2], wc[k], __builtin_shufflevector(fb, fb, 0, 1));
        pkfma(acc[3], wc[k], __builtin_shufflevector(fb, fb, 2, 3));
    }
}

// Build the union active list (ascending neuron order) + rank-indexed
// per-row step-mask floats. m7 = this thread's 7 firing bits.
__device__ __forceinline__ int build_union(const unsigned long long (*zm7)[8],
                                           int* act, float (*fmp)[8],
                                           int wid, int lane, int tid, int m7) {
    unsigned long long um[8];
    #pragma unroll
    for (int q = 0; q < 8; ++q) {
        unsigned long long u = zm7[0][q];
        #pragma unroll
        for (int s = 1; s < SPIKE_STEPS; ++s) u |= zm7[s][q];
        um[q] = u;
    }
    int pre = 0, total = 0;
    #pragma unroll
    for (int q = 0; q < 8; ++q) {
        int p = __popcll(um[q]);
        total += p;
        if (q < wid) pre += p;
    }
    if (m7 != 0) {
        int rank = pre + __popcll(um[wid] & ((1ull << lane) - 1ull));
        act[rank] = tid;
        f32x4 v0, v4;
        #pragma unroll
        for (int s = 0; s < 4; ++s) v0[s] = ((m7 >> s) & 1) ? 1.0f : 0.0f;
        #pragma unroll
        for (int s = 0; s < 3; ++s) v4[s] = ((m7 >> (4 + s)) & 1) ? 1.0f : 0.0f;
        v4[3] = 0.f;
        *reinterpret_cast<f32x4*>(&fmp[rank][0]) = v0;
        *reinterpret_cast<f32x4*>(&fmp[rank][4]) = v4;
    }
    int npad = (total + 15) & ~15;
    if (tid < npad - total) {
        act[total + tid] = 0;                          // row 0, mask 0 pad
        const f32x4 z = {0.f, 0.f, 0.f, 0.f};
        *reinterpret_cast<f32x4*>(&fmp[total + tid][0]) = z;
        *reinterpret_cast<f32x4*>(&fmp[total + tid][4]) = z;
    }
    return npad;
}

// Two-stage pipeline: even blocks = producer (layer0+layer1), odd = consumer
// (layer2+output). Handoff granularity = one seq step (7 masks at once).
// 3 barriers per seq step per role (xs double-buffered; spin+load merged).
__launch_bounds__(512, 1)
__global__ void snn_pipe_kernel(const float* __restrict__ x,     // [256,128,96]
                                const float* __restrict__ Wout,  // [2,512]
                                const float* __restrict__ betas, // [3]
                                const float* __restrict__ thrs,  // [3]
                                const float* __restrict__ W0T,   // [96,512]
                                const float* __restrict__ W1T,   // [512,512]
                                const float* __restrict__ W2T,   // [512,512]
                                unsigned long long* __restrict__ zbuf,
                                int* __restrict__ ctr,
                                float* __restrict__ out)         // [256,128,2]
{
    const int b    = blockIdx.x >> 1;
    const int role = blockIdx.x & 1;
    const int tid  = threadIdx.x;
    const int lane = tid & 63;
    const int wid  = tid >> 6;

    __shared__ float xs[2][IN_DIM];
    __shared__ unsigned long long zm7[SPIKE_STEPS][8];
    __shared__ int act[HIDDEN];
    __shared__ __align__(16) float fmp[HIDDEN][8];   // rank-indexed masks
    __shared__ float red[16];

    if (role == 0) {
        // ---------------- producer: layer0 + layer1 ----------------
        const float beta0 = betas[0], beta1 = betas[1];
        const float thr0  = thrs[0],  thr1  = thrs[1];
        float mem0 = 0.f, mem1 = 0.f;
        unsigned long long* zb = zbuf + (size_t)b * SEQ_LEN * 56;

        if (tid < IN_DIM) xs[0][tid] = x[(0 * BATCH + b) * IN_DIM + tid];
        __syncthreads();                                        // prologue

        for (int i = 0; i < SEQ_LEN; ++i) {
            const int cur = i & 1;

            float cur0 = 0.f;
            #pragma unroll 8
            for (int k = 0; k < IN_DIM; ++k)
                cur0 = __fmaf_rn(xs[cur][k], W0T[k * HIDDEN + tid], cur0);

            // prefetch next step's x slice into the other xs buffer
            // (visibility guaranteed by B2/B3 before next use; no overlap
            // hazard: different buffer than the one being read above)
            if (i + 1 < SEQ_LEN && tid < IN_DIM)
                xs[cur ^ 1][tid] = x[((i + 1) * BATCH + b) * IN_DIM + tid];

            // layer-0 recurrence is autonomous within the seq step:
            // compute all 7 z0 masks upfront.
            int m7 = 0;
            #pragma unroll
            for (int s = 0; s < SPIKE_STEPS; ++s) {
                bool reset0 = (mem0 - thr0) > 0.f;
                mem0 = reset0 ? 0.f : __fadd_rn(__fmul_rn(beta0, mem0), cur0);
                bool z0 = (mem0 - thr0) > 0.f;
                m7 |= (int)z0 << s;
                unsigned long long bal = __ballot(z0);
                if (lane == 0) zm7[s][wid] = bal;
            }
            __syncthreads();                                    // B1: zm7 ready

            int npad = build_union(zm7, act, fmp, wid, lane, tid, m7);
            __syncthreads();                                    // B2: act/fmp ready

            f32x2 acc[4] = {{0.f,0.f},{0.f,0.f},{0.f,0.f},{0.f,0.f}};
            union_sum7(W1T, act, fmp, npad, tid, acc);
            const float accs[SPIKE_STEPS] =
                {acc[0].x, acc[0].y, acc[1].x, acc[1].y, acc[2].x, acc[2].y, acc[3].x};

            // layer-1 recurrence over the 7 steps, emit z1 masks
            #pragma unroll
            for (int s = 0; s < SPIKE_STEPS; ++s) {
                bool reset1 = (mem1 - thr1) > 0.f;
                mem1 = reset1 ? 0.f : __fadd_rn(__fmul_rn(beta1, mem1), accs[s]);
                bool z1 = (mem1 - thr1) > 0.f;
                unsigned long long bal1 = __ballot(z1);
                if (lane == 0)
                    __hip_atomic_store(&zb[(size_t)i * 56 + s * 8 + wid], bal1,
                                       __ATOMIC_RELAXED, __HIP_MEMORY_SCOPE_AGENT);
            }
            __syncthreads();   // B3: all waves' mask stores drained (vmcnt 0)
            if (tid == 0)
                __hip_atomic_store(&ctr[b], i + 1,
                                   __ATOMIC_RELAXED, __HIP_MEMORY_SCOPE_AGENT);
        }
    } else {
        // ---------------- consumer: layer2 + output ----------------
        const float beta2 = betas[2];
        const float thr2  = thrs[2];
        const float wo0 = Wout[tid];
        const float wo1 = Wout[HIDDEN + tid];
        float mem2 = 0.f;
        // Deferred output reduction: per-thread integrator a, prefix
        // accumulator w; one cross-thread reduction per seq step.
        float a0s = 0.f, a1s = 0.f;
        const unsigned long long* zb = zbuf + (size_t)b * SEQ_LEN * 56;

        for (int i = 0; i < SEQ_LEN; ++i) {
            // merged spin + mask load: the 56 loader threads (wave 0) spin on
            // the same ctr cacheline, then fetch the masks; one barrier total.
            if (tid < 56) {
                while (__hip_atomic_load(&ctr[b], __ATOMIC_RELAXED,
                                         __HIP_MEMORY_SCOPE_AGENT) < i + 1)
                    __builtin_amdgcn_s_sleep(1);
                ((unsigned long long*)zm7)[tid] =
                    __hip_atomic_load(&zb[(size_t)i * 56 + tid],
                                      __ATOMIC_RELAXED, __HIP_MEMORY_SCOPE_AGENT);
            }
            __syncthreads();                                    // B1: zm7 ready

            int m7 = 0;
            #pragma unroll
            for (int s = 0; s < SPIKE_STEPS; ++s)
                m7 |= (int)((zm7[s][wid] >> lane) & 1ull) << s;

            int npad = build_union(zm7, act, fmp, wid, lane, tid, m7);
            __syncthreads();                                    // B2: act/fmp ready

            f32x2 acc[4] = {{0.f,0.f},{0.f,0.f},{0.f,0.f},{0.f,0.f}};
            union_sum7(W2T, act, fmp, npad, tid, acc);
            const float accs[SPIKE_STEPS] =
                {acc[0].x, acc[0].y, acc[1].x, acc[1].y, acc[2].x, acc[2].y, acc[3].x};

            float w0 = 0.f, w1 = 0.f;
            #pragma unroll
            for (int s = 0; s < SPIKE_STEPS; ++s) {
                bool reset2 = (mem2 - thr2) > 0.f;
                mem2 = reset2 ? 0.f : __fadd_rn(__fmul_rn(beta2, mem2), accs[s]);
                bool z2 = (mem2 - thr2) > 0.f;
                a0s += z2 ? wo0 : 0.f;
                a1s += z2 ? wo1 : 0.f;
                w0 += a0s;
                w1 += a1s;
            }

            // one cross-thread reduction per seq step
            float r0 = w0, r1 = w1;
            #pragma unroll
            for (int off = 32; off > 0; off >>= 1) {
                r0 += __shfl_down(r0, off);
                r1 += __shfl_down(r1, off);
            }
            if (lane == 0) { red[wid * 2] = r0; red[wid * 2 + 1] = r1; }
            __syncthreads();                                    // B3
            if (tid == 0) {
                float s0 = 0.f, s1 = 0.f;
                #pragma unroll
                for (int q = 0; q < 8; ++q) { s0 += red[q * 2]; s1 += red[q * 2 + 1]; }
                out[(i * BATCH + b) * OUT_DIM + 0] = s0 / 7.0f;
                out[(i * BATCH + b) * OUT_DIM + 1] = s1 / 7.0f;
            }
            // next write to red is a full seq step away (>=2 barriers) and
            // tid0's read precedes its next barrier => no extra barrier.
        }
    }
}

extern "C" void kernel_launch(void* const* d_in, const int* in_sizes, int n_in,
                              void* d_out, int out_size, void* d_ws, size_t ws_size,
                              hipStream_t stream) {
    const float* x     = (const float*)d_in[0];
    const float* W0    = (const float*)d_in[1];
    const float* W1    = (const float*)d_in[2];
    const float* W2    = (const float*)d_in[3];
    const float* Wout  = (const float*)d_in[4];
    const float* betas = (const float*)d_in[5];
    const float* thrs  = (const float*)d_in[6];
    float* out = (float*)d_out;

    float* ws  = (float*)d_ws;
    float* W0T = ws + W0T_OFF;
    float* W1T = ws + W1T_OFF;
    float* W2T = ws + W2T_OFF;
    int* ctr = (int*)((char*)d_ws + CTR_BYTE_OFF);
    unsigned long long* zbuf = (unsigned long long*)((char*)d_ws + ZBUF_BYTE_OFF);

    {
        int n = HIDDEN * IN_DIM;
        transpose_kernel<<<(n + 255) / 256, 256, 0, stream>>>(W0, W0T, HIDDEN, IN_DIM);
    }
    {
        int n = HIDDEN * HIDDEN;
        transpose_kernel<<<(n + 255) / 256, 256, 0, stream>>>(W1, W1T, HIDDEN, HIDDEN);
        transpose_kernel<<<(n + 255) / 256, 256, 0, stream>>>(W2, W2T, HIDDEN, HIDDEN);
    }

    hipMemsetAsync((char*)d_ws + CTR_BYTE_OFF, 0, 1024, stream);

    snn_pipe_kernel<<<2 * BATCH, HIDDEN, 0, stream>>>(
        x, Wout, betas, thrs, W0T, W1T, W2T, zbuf, ctr, out);
}